// Round 7
// baseline (828.155 us; speedup 1.0000x reference)
//
#include <hip/hip_runtime.h>

#define IMG 512
#define HALO 5
#define BAND 8
#define NB 16          // bands per block (128 rows / 8)
#define RING 18        // ring slots == live rows (8 + 2*5) -> 18448 B -> 8 blocks/CU

// Gaussian window, sigma=1.5, ws=11, normalized (matches reference _make_window)
__device__ constexpr float WT[11] = {
    1.0283800e-03f, 7.5987582e-03f, 3.6000773e-02f, 1.0936070e-01f,
    2.1300553e-01f, 2.6601172e-01f, 2.1300553e-01f, 1.0936070e-01f,
    3.6000773e-02f, 7.5987582e-03f, 1.0283800e-03f
};

typedef float f2 __attribute__((ext_vector_type(2)));

__device__ __forceinline__ f2 pkfma(f2 a, f2 b, f2 c) {
    return __builtin_elementwise_fma(a, b, c);   // -> v_pk_fma_f32
}

// Raw workgroup barrier: drain LDS only, leave global loads in flight.
#define LGKM_BARRIER() asm volatile("s_waitcnt lgkmcnt(0)\n\ts_barrier" ::: "memory")

// Horizontal 11-tap blur of a 16-col window -> 2 output cols.
// J0 = window index of the first tap of output 0 (compile-time).
template<int J0>
__device__ __forceinline__ void hblur2(const float4* qx, const float4* qy,
                                       f2* m, f2* t2)
{
    float X[16], Y[16];
    #pragma unroll
    for (int t = 0; t < 4; ++t) {
        X[4*t+0]=qx[t].x; X[4*t+1]=qx[t].y; X[4*t+2]=qx[t].z; X[4*t+3]=qx[t].w;
        Y[4*t+0]=qy[t].x; Y[4*t+1]=qy[t].y; Y[4*t+2]=qy[t].z; Y[4*t+3]=qy[t].w;
    }
    m[0] = f2{0.f,0.f}; m[1] = f2{0.f,0.f};
    t2[0] = f2{0.f,0.f}; t2[1] = f2{0.f,0.f};
    #pragma unroll
    for (int j = J0; j <= J0 + 11; ++j) {
        const float x = X[j], y = Y[j];
        const f2 v  = {x, y};
        const f2 s2 = {fmaf(x, x, y*y), x*y};
        #pragma unroll
        for (int o = 0; o < 2; ++o) {
            const int k = j - J0 - o;                // tap index for output o
            if (0 <= k && k <= 10) {
                const f2 w = {WT[k], WT[k]};
                m[o]  = pkfma(w, v,  m[o]);
                t2[o] = pkfma(w, s2, t2[o]);
            }
        }
    }
}

__global__ __launch_bounds__(256, 8)
void ssim_main(const float* __restrict__ img1, const float* __restrict__ img2,
               float* __restrict__ part)
{
    constexpr float C1 = 1.0e-4f;
    constexpr float C2 = 9.0e-4f;

    // Ring of horizontal-blur results, 4 fused channels per px:
    //   (bx = h-blur(x), by = h-blur(y), bs = h-blur(x^2+y^2), bp = h-blur(x*y))
    // Physical column is XOR-swizzled: phys = c ^ (c>>2).
    // RING=18 slots -> 8 blocks/CU == the 8 queued blocks/CU: single
    // generation, all 32 waves/CU resident for the whole kernel.
    __shared__ float4 sH[RING][64];      // 18432 B
    __shared__ float  sRed[4];

    const int bx      = blockIdx.x;
    const int n       = bx >> 5;          // image 0..63
    const int stripe  = (bx >> 2) & 7;    // 64-col stripe
    const int quarter = bx & 3;           // 128-row quarter
    const int gx0     = stripe << 6;
    const int base    = quarter << 7;
    const int tid     = threadIdx.x;
    const bool edge   = (stripe == 0) | (stripe == 7);

    const float* __restrict__ base1 = img1 + (size_t)n * IMG * IMG;
    const float* __restrict__ base2 = img2 + (size_t)n * IMG * IMG;

    float acc = 0.0f;

    // ---- store-task geometry: 8 rows x 16 cg x 2 sub = 256 tasks/band.
    // sub is wave-uniform (tid>>7): waves 0,1 do sub=0, waves 2,3 sub=1.
    const int sub = tid >> 7;
    const int idx = tid & 127;
    const int rr  = idx >> 4;                        // 0..7 row in store band
    const int cg  = idx & 15;
    const int lc0 = (cg << 2) + (sub << 1);          // logical col 0..62 (even)
    const int fb  = gx0 + (cg << 2) - 8 + (sub << 2);// float4-aligned window base

    // ---- load 16-col window (4 aligned float4/img), h-blur, store 2 cols
    auto doStore2 = [&](const float* r1, const float* r2, bool rowok, int slot) {
        float4 qx[4], qy[4];
        if (rowok & (!edge)) {
            #pragma unroll
            for (int t = 0; t < 4; ++t) {
                qx[t] = ((const float4*)r1)[t];
                qy[t] = ((const float4*)r2)[t];
            }
        } else {
            #pragma unroll
            for (int t = 0; t < 4; ++t) {
                const int gc = fb + (t << 2);        // aligned: all-in or all-out
                const bool ok = rowok && (gc >= 0) && (gc < IMG);
                qx[t] = ok ? ((const float4*)r1)[t] : make_float4(0.f,0.f,0.f,0.f);
                qy[t] = ok ? ((const float4*)r2)[t] : make_float4(0.f,0.f,0.f,0.f);
            }
        }
        f2 m[2], t2[2];
        if (sub == 0) hblur2<3>(qx, qy, m, t2);      // wave-uniform branch
        else          hblur2<1>(qx, qy, m, t2);
        #pragma unroll
        for (int o = 0; o < 2; ++o) {
            const int c  = lc0 + o;
            const int wc = c ^ (c >> 2);             // phys col = c ^ (c>>2)
            sH[slot][wc] = make_float4(m[o].x, m[o].y, t2[o].x, t2[o].y);
        }
    };

    // ---- vertical blur + SSIM for one band (2 rows/thread)
    const int col  = tid & 63;
    const int rcol = col ^ (col >> 2);               // phys read col
    const int wv   = __builtin_amdgcn_readfirstlane(tid >> 6);

    auto vertical = [&](int sb_) {
        const int d0 = sb_ + (wv << 1);              // uniform, <= 22
        f2 ma[2] = {f2{0.f,0.f},f2{0.f,0.f}};
        f2 sa[2] = {f2{0.f,0.f},f2{0.f,0.f}};
        #pragma unroll
        for (int i = 0; i < 12; ++i) {
            int s = d0 + i;                          // <= 33 -> one cond sub
            s -= (s >= RING) ? RING : 0;
            const float4 q = sH[s][rcol];
            const f2 v = {q.x, q.y};                 // (bx, by)
            const f2 u = {q.z, q.w};                 // (bs, bp)
            #pragma unroll
            for (int o = 0; o < 2; ++o) {
                const int k = i - o;                 // tap index for row o
                if (0 <= k && k <= 10) {
                    const f2 w = {WT[k], WT[k]};
                    ma[o] = pkfma(w, v, ma[o]);
                    sa[o] = pkfma(w, u, sa[o]);
                }
            }
        }
        #pragma unroll
        for (int o = 0; o < 2; ++o) {
            const f2 m   = ma[o];
            const f2 tt  = sa[o];
            const f2 msq = m * m;                    // (mu1^2, mu2^2)
            const float mu12  = m.x * m.y;
            const float musum = msq.x + msq.y;
            const float g12 = tt.y - mu12;           // sigma12
            const float gs  = tt.x - musum;          // sigma1^2 + sigma2^2
            const float num = fmaf(2.f, mu12, C1) * fmaf(2.f, g12, C2);
            const float den = (musum + C1) * (gs + C2);
            acc = fmaf(num, __builtin_amdgcn_rcpf(den), acc);
        }
    };

    // ---- prologue: h-blur rows base-5 .. base+12 into slots 0..17.
    // 3 passes of 8 rows x 16 cg x 2 sub; sub stays wave-uniform.
    #pragma unroll
    for (int r = 0; r < 3; ++r) {
        const int i = (r << 3) + rr;                 // slot 0..17 (pass 2: 16,17)
        if (i < RING) {
            const int gr = base - HALO + i;          // max 384+12 < 512 always
            const float* r1 = base1 + (ptrdiff_t)gr * IMG + fb;
            const float* r2 = base2 + (ptrdiff_t)gr * IMG + fb;
            doStore2(r1, r2, gr >= 0, i);
        }
    }

    // ---- steady-state pointers: store-band b writes rows base+8b+13+rr
    const float* p1 = base1 + (ptrdiff_t)(base + 13 + rr) * IMG + fb;
    const float* p2 = base2 + (ptrdiff_t)(base + 13 + rr) * IMG + fb;

    // ---- main loop: vertical, then load+blur+store for next band.
    // Loads are issued post-WAR-barrier and consumed immediately; the vmcnt
    // stall is hidden by the 8 resident blocks/CU (barriers are per-block).
    int sb = 0;                                      // (8*b) mod RING, scalar
    for (int b = 0; b < NB; ++b) {
        LGKM_BARRIER();                              // ring rows for band b ready
        vertical(sb);
        LGKM_BARRIER();                              // vert reads done (WAR on ring)

        if (b < NB - 1) {
            const int grow = base + (b << 3) + 13 + rr;
            int t = sb + rr;                         // slot of row grow
            t -= (t >= RING) ? RING : 0;
            // rows OOB only possible when quarter==3 && b==14 (509..516)
            doStore2(p1, p2, (unsigned)grow < (unsigned)IMG, t);
            p1 += BAND * IMG;
            p2 += BAND * IMG;
        }
        sb += BAND; sb -= (sb >= RING) ? RING : 0;
    }

    // ---- block reduction -> one partial per block
    #pragma unroll
    for (int off = 32; off > 0; off >>= 1)
        acc += __shfl_down(acc, off, 64);
    if ((tid & 63) == 0) sRed[tid >> 6] = acc;
    LGKM_BARRIER();
    if (tid == 0) part[bx] = sRed[0] + sRed[1] + sRed[2] + sRed[3];
}

__global__ void ssim_finalize(const float* __restrict__ part, float* __restrict__ out)
{
    __shared__ double sD[4];
    double s = 0.0;
    const int t = threadIdx.x;
    for (int i = t; i < 2048; i += 256) s += (double)part[i];
    #pragma unroll
    for (int off = 32; off > 0; off >>= 1)
        s += __shfl_down(s, off, 64);
    if ((t & 63) == 0) sD[t >> 6] = s;
    __syncthreads();
    if (t == 0) out[0] = (float)((sD[0] + sD[1] + sD[2] + sD[3]) * (1.0 / 16777216.0));
}

extern "C" void kernel_launch(void* const* d_in, const int* in_sizes, int n_in,
                              void* d_out, int out_size, void* d_ws, size_t ws_size,
                              hipStream_t stream)
{
    const float* img1 = (const float*)d_in[0];
    const float* img2 = (const float*)d_in[1];
    float* out  = (float*)d_out;
    float* part = (float*)d_ws;      // 2048 floats of scratch

    ssim_main<<<2048, 256, 0, stream>>>(img1, img2, part);
    ssim_finalize<<<1, 256, 0, stream>>>(part, out);
}

// Round 8
// 202.962 us; speedup vs baseline: 4.0803x; 4.0803x over previous
//
#include <hip/hip_runtime.h>

#define IMG 512
#define HALO 5
#define BAND 8
#define NB 16          // bands per block (128 rows / 8)
#define RING 18        // ring slots == live rows (8 + 2*5) -> 18.4 KB -> 8 blocks/CU

// Gaussian window, sigma=1.5, ws=11, normalized (matches reference _make_window)
__device__ constexpr float WT[11] = {
    1.0283800e-03f, 7.5987582e-03f, 3.6000773e-02f, 1.0936070e-01f,
    2.1300553e-01f, 2.6601172e-01f, 2.1300553e-01f, 1.0936070e-01f,
    3.6000773e-02f, 7.5987582e-03f, 1.0283800e-03f
};

typedef float f2 __attribute__((ext_vector_type(2)));

__device__ __forceinline__ f2 pkfma(f2 a, f2 b, f2 c) {
    return __builtin_elementwise_fma(a, b, c);   // -> v_pk_fma_f32
}

// Raw workgroup barrier: drain LDS only, leave global loads in flight.
#define LGKM_BARRIER() asm volatile("s_waitcnt lgkmcnt(0)\n\ts_barrier" ::: "memory")

// Horizontal 11-tap blur of a 16-col window -> 2 output cols.
// J0 = window index of the first tap of output 0 (compile-time).
template<int J0>
__device__ __forceinline__ void hblur2(const float4* qx, const float4* qy,
                                       f2* m, f2* t2)
{
    float X[16], Y[16];
    #pragma unroll
    for (int t = 0; t < 4; ++t) {
        X[4*t+0]=qx[t].x; X[4*t+1]=qx[t].y; X[4*t+2]=qx[t].z; X[4*t+3]=qx[t].w;
        Y[4*t+0]=qy[t].x; Y[4*t+1]=qy[t].y; Y[4*t+2]=qy[t].z; Y[4*t+3]=qy[t].w;
    }
    m[0] = f2{0.f,0.f}; m[1] = f2{0.f,0.f};
    t2[0] = f2{0.f,0.f}; t2[1] = f2{0.f,0.f};
    #pragma unroll
    for (int j = J0; j <= J0 + 11; ++j) {
        const float x = X[j], y = Y[j];
        const f2 v  = {x, y};
        const f2 s2 = {fmaf(x, x, y*y), x*y};
        #pragma unroll
        for (int o = 0; o < 2; ++o) {
            const int k = j - J0 - o;                // tap index for output o
            if (0 <= k && k <= 10) {
                const f2 w = {WT[k], WT[k]};
                m[o]  = pkfma(w, v,  m[o]);
                t2[o] = pkfma(w, s2, t2[o]);
            }
        }
    }
}

// NOTE: (256,8) makes the allocator clamp to 32 VGPR (unified-file split) and
// spill ~2.8 GB (R6/R7). (256,4) gives a 128-reg budget; actual usage <=64
// still lets the HARDWARE run 8 blocks/CU with RING=18's 18.4 KB LDS.
__global__ __launch_bounds__(256, 4)
void ssim_main(const float* __restrict__ img1, const float* __restrict__ img2,
               float* __restrict__ part)
{
    constexpr float C1 = 1.0e-4f;
    constexpr float C2 = 9.0e-4f;

    // Ring of horizontal-blur results, 4 fused channels per px:
    //   (bx = h-blur(x), by = h-blur(y), bs = h-blur(x^2+y^2), bp = h-blur(x*y))
    // Physical column is XOR-swizzled: phys = c ^ (c>>2).
    __shared__ float4 sH[RING][64];      // 18432 B
    __shared__ float  sRed[4];

    const int bx      = blockIdx.x;
    const int n       = bx >> 5;          // image 0..63
    const int stripe  = (bx >> 2) & 7;    // 64-col stripe
    const int quarter = bx & 3;           // 128-row quarter
    const int gx0     = stripe << 6;
    const int base    = quarter << 7;
    const int tid     = threadIdx.x;
    const bool edge   = (stripe == 0) | (stripe == 7);

    const float* __restrict__ base1 = img1 + (size_t)n * IMG * IMG;
    const float* __restrict__ base2 = img2 + (size_t)n * IMG * IMG;

    float acc = 0.0f;

    // ---- store-task geometry: 8 rows x 16 cg x 2 sub = 256 tasks/band.
    // sub is wave-uniform (tid>>7): waves 0,1 do sub=0, waves 2,3 sub=1.
    const int sub = tid >> 7;
    const int idx = tid & 127;
    const int rr  = idx >> 4;                        // 0..7 row in store band
    const int cg  = idx & 15;
    const int lc0 = (cg << 2) + (sub << 1);          // logical col 0..62 (even)
    const int fb  = gx0 + (cg << 2) - 8 + (sub << 2);// float4-aligned window base

    // ---- load 16-col window (4 aligned float4/img), h-blur, store 2 cols
    auto doStore2 = [&](const float* r1, const float* r2, bool rowok, int slot) {
        float4 qx[4], qy[4];
        if (rowok & (!edge)) {
            #pragma unroll
            for (int t = 0; t < 4; ++t) {
                qx[t] = ((const float4*)r1)[t];
                qy[t] = ((const float4*)r2)[t];
            }
        } else {
            #pragma unroll
            for (int t = 0; t < 4; ++t) {
                const int gc = fb + (t << 2);        // aligned: all-in or all-out
                const bool ok = rowok && (gc >= 0) && (gc < IMG);
                qx[t] = ok ? ((const float4*)r1)[t] : make_float4(0.f,0.f,0.f,0.f);
                qy[t] = ok ? ((const float4*)r2)[t] : make_float4(0.f,0.f,0.f,0.f);
            }
        }
        f2 m[2], t2[2];
        if (sub == 0) hblur2<3>(qx, qy, m, t2);      // wave-uniform branch
        else          hblur2<1>(qx, qy, m, t2);
        #pragma unroll
        for (int o = 0; o < 2; ++o) {
            const int c  = lc0 + o;
            const int wc = c ^ (c >> 2);             // phys col = c ^ (c>>2)
            sH[slot][wc] = make_float4(m[o].x, m[o].y, t2[o].x, t2[o].y);
        }
    };

    // ---- vertical blur + SSIM for one band (2 rows/thread)
    const int col  = tid & 63;
    const int rcol = col ^ (col >> 2);               // phys read col
    const int wv   = __builtin_amdgcn_readfirstlane(tid >> 6);

    auto vertical = [&](int sb_) {
        const int d0 = sb_ + (wv << 1);              // uniform, <= 22
        f2 ma[2] = {f2{0.f,0.f},f2{0.f,0.f}};
        f2 sa[2] = {f2{0.f,0.f},f2{0.f,0.f}};
        #pragma unroll
        for (int i = 0; i < 12; ++i) {
            int s = d0 + i;                          // <= 33 -> one cond sub
            s -= (s >= RING) ? RING : 0;
            const float4 q = sH[s][rcol];
            const f2 v = {q.x, q.y};                 // (bx, by)
            const f2 u = {q.z, q.w};                 // (bs, bp)
            #pragma unroll
            for (int o = 0; o < 2; ++o) {
                const int k = i - o;                 // tap index for row o
                if (0 <= k && k <= 10) {
                    const f2 w = {WT[k], WT[k]};
                    ma[o] = pkfma(w, v, ma[o]);
                    sa[o] = pkfma(w, u, sa[o]);
                }
            }
        }
        #pragma unroll
        for (int o = 0; o < 2; ++o) {
            const f2 m   = ma[o];
            const f2 tt  = sa[o];
            const f2 msq = m * m;                    // (mu1^2, mu2^2)
            const float mu12  = m.x * m.y;
            const float musum = msq.x + msq.y;
            const float g12 = tt.y - mu12;           // sigma12
            const float gs  = tt.x - musum;          // sigma1^2 + sigma2^2
            const float num = fmaf(2.f, mu12, C1) * fmaf(2.f, g12, C2);
            const float den = (musum + C1) * (gs + C2);
            acc = fmaf(num, __builtin_amdgcn_rcpf(den), acc);
        }
    };

    // ---- prologue: h-blur rows base-5 .. base+12 into slots 0..17.
    // 3 passes of 8 rows x 16 cg x 2 sub; sub stays wave-uniform.
    #pragma unroll
    for (int r = 0; r < 3; ++r) {
        const int i = (r << 3) + rr;                 // slot 0..17 (pass 2: 16,17)
        if (i < RING) {
            const int gr = base - HALO + i;          // max 384+12 < 512 always
            const float* r1 = base1 + (ptrdiff_t)gr * IMG + fb;
            const float* r2 = base2 + (ptrdiff_t)gr * IMG + fb;
            doStore2(r1, r2, gr >= 0, i);
        }
    }

    // ---- steady-state pointers: store-band b writes rows base+8b+13+rr
    const float* p1 = base1 + (ptrdiff_t)(base + 13 + rr) * IMG + fb;
    const float* p2 = base2 + (ptrdiff_t)(base + 13 + rr) * IMG + fb;

    // ---- main loop: vertical, then load+blur+store for next band.
    // Loads are issued post-WAR-barrier and consumed immediately; the vmcnt
    // stall is hidden by the 8 resident blocks/CU (barriers are per-block).
    int sb = 0;                                      // (8*b) mod RING, scalar
    for (int b = 0; b < NB; ++b) {
        LGKM_BARRIER();                              // ring rows for band b ready
        vertical(sb);
        LGKM_BARRIER();                              // vert reads done (WAR on ring)

        if (b < NB - 1) {
            const int grow = base + (b << 3) + 13 + rr;
            int t = sb + rr;                         // slot of row grow
            t -= (t >= RING) ? RING : 0;
            // rows OOB only possible when quarter==3 && b==14 (509..516)
            doStore2(p1, p2, (unsigned)grow < (unsigned)IMG, t);
            p1 += BAND * IMG;
            p2 += BAND * IMG;
        }
        sb += BAND; sb -= (sb >= RING) ? RING : 0;
    }

    // ---- block reduction -> one partial per block
    #pragma unroll
    for (int off = 32; off > 0; off >>= 1)
        acc += __shfl_down(acc, off, 64);
    if ((tid & 63) == 0) sRed[tid >> 6] = acc;
    LGKM_BARRIER();
    if (tid == 0) part[bx] = sRed[0] + sRed[1] + sRed[2] + sRed[3];
}

__global__ void ssim_finalize(const float* __restrict__ part, float* __restrict__ out)
{
    __shared__ double sD[4];
    double s = 0.0;
    const int t = threadIdx.x;
    for (int i = t; i < 2048; i += 256) s += (double)part[i];
    #pragma unroll
    for (int off = 32; off > 0; off >>= 1)
        s += __shfl_down(s, off, 64);
    if ((t & 63) == 0) sD[t >> 6] = s;
    __syncthreads();
    if (t == 0) out[0] = (float)((sD[0] + sD[1] + sD[2] + sD[3]) * (1.0 / 16777216.0));
}

extern "C" void kernel_launch(void* const* d_in, const int* in_sizes, int n_in,
                              void* d_out, int out_size, void* d_ws, size_t ws_size,
                              hipStream_t stream)
{
    const float* img1 = (const float*)d_in[0];
    const float* img2 = (const float*)d_in[1];
    float* out  = (float*)d_out;
    float* part = (float*)d_ws;      // 2048 floats of scratch

    ssim_main<<<2048, 256, 0, stream>>>(img1, img2, part);
    ssim_finalize<<<1, 256, 0, stream>>>(part, out);
}

// Round 9
// 172.734 us; speedup vs baseline: 4.7944x; 1.1750x over previous
//
#include <hip/hip_runtime.h>

#define IMG 512
#define HALO 5
#define BAND 16
#define NB 8           // bands per block (128 rows / 16)
#define RING 26        // ring slots == live rows (16 + 2*5)

// Gaussian window, sigma=1.5, ws=11, normalized (matches reference _make_window)
#define W0 1.0283800e-03f
#define W1 7.5987582e-03f
#define W2 3.6000773e-02f
#define W3 1.0936070e-01f
#define W4 2.1300553e-01f
#define W5 2.6601172e-01f

typedef float f2 __attribute__((ext_vector_type(2)));

__device__ __forceinline__ f2 pkfma(f2 a, f2 b, f2 c) {
    return __builtin_elementwise_fma(a, b, c);   // -> v_pk_fma_f32
}

// Raw workgroup barrier: drain LDS only, leave global loads in flight.
#define LGKM_BARRIER() asm volatile("s_waitcnt lgkmcnt(0)\n\ts_barrier" ::: "memory")

__global__ __launch_bounds__(256, 4)
void ssim_main(const float* __restrict__ img1, const float* __restrict__ img2,
               float* __restrict__ part)
{
    constexpr float C1 = 1.0e-4f;
    constexpr float C2 = 9.0e-4f;

    // v_pk_fma_f32 is VOP3P: literals are ILLEGAL operands, so every
    // f2{W,W} built in-loop costs 2 v_mov. Pin the 11 weight pairs in
    // VGPRs ONCE; the empty asm is an opaque def the compiler can't
    // rematerialize through. (~2.1K inst/thread saved vs in-loop movs.)
    const float Wt[11] = {W0,W1,W2,W3,W4,W5,W4,W3,W2,W1,W0};
    f2 W2r[11];
    #pragma unroll
    for (int k = 0; k < 11; ++k) {
        W2r[k] = f2{Wt[k], Wt[k]};
        asm volatile("" : "+v"(W2r[k]));
    }

    // Ring of horizontal-blur results, 4 fused channels per px:
    //   (bx = h-blur(x), by = h-blur(y), bs = h-blur(x^2+y^2), bp = h-blur(x*y))
    // Physical column is XOR-swizzled: phys = c ^ (c>>2).
    __shared__ float4 sH[RING][64];      // 26624 B
    __shared__ float  sRed[4];

    const int bx      = blockIdx.x;
    const int n       = bx >> 5;          // image 0..63
    const int stripe  = (bx >> 2) & 7;    // 64-col stripe
    const int quarter = bx & 3;           // 128-row quarter
    const int gx0     = stripe << 6;
    const int base    = quarter << 7;
    const int tid     = threadIdx.x;
    const bool edge   = (stripe == 0) | (stripe == 7);

    const float* __restrict__ base1 = img1 + (size_t)n * IMG * IMG;
    const float* __restrict__ base2 = img2 + (size_t)n * IMG * IMG;

    float acc = 0.0f;

    // ---- predicated 20-col window load (5 aligned float4 per image)
    auto loadRowP = [&](const float* r1, const float* r2, bool rok, int gcb_,
                        float4* px, float4* py) {
        #pragma unroll
        for (int t = 0; t < 5; ++t) {
            int gc = gcb_ - 8 + (t << 2);
            bool ok = rok && (gc >= 0) && (gc < IMG);
            px[t] = ok ? ((const float4*)r1)[t] : make_float4(0.f,0.f,0.f,0.f);
            py[t] = ok ? ((const float4*)r2)[t] : make_float4(0.f,0.f,0.f,0.f);
        }
    };

    // ---- horizontal blur (accumulate-by-input-index) -> ring[slot], 4 cols
    auto horizStore = [&](const float4* px, const float4* py, int slot, int cg) {
        f2 m[4]  = {f2{0.f,0.f},f2{0.f,0.f},f2{0.f,0.f},f2{0.f,0.f}};
        f2 t2[4] = {f2{0.f,0.f},f2{0.f,0.f},f2{0.f,0.f},f2{0.f,0.f}};
        #pragma unroll
        for (int t = 0; t < 5; ++t) {
            #pragma unroll
            for (int e = 0; e < 4; ++e) {
                const int j = (t << 2) + e;          // 0..19, taps use 3..16
                if (j < 3 || j > 16) continue;
                const float x = (e==0) ? px[t].x : (e==1) ? px[t].y : (e==2) ? px[t].z : px[t].w;
                const float y = (e==0) ? py[t].x : (e==1) ? py[t].y : (e==2) ? py[t].z : py[t].w;
                const f2 v  = {x, y};
                const f2 s2 = {fmaf(x, x, y*y), x*y};
                #pragma unroll
                for (int o = 0; o < 4; ++o) {
                    const int k = j - 3 - o;         // tap index for output o
                    if (0 <= k && k <= 10) {
                        m[o]  = pkfma(W2r[k], v,  m[o]);
                        t2[o] = pkfma(W2r[k], s2, t2[o]);
                    }
                }
            }
        }
        const int c4 = cg << 2;
        #pragma unroll
        for (int o = 0; o < 4; ++o) {
            const int wc = (c4 + o) ^ cg;            // phys col = c ^ (c>>2)
            sH[slot][wc] = make_float4(m[o].x, m[o].y, t2[o].x, t2[o].y);
        }
    };

    // ---- steady-state thread geometry
    const int rr  = tid >> 4;                        // 0..15
    const int cgs = tid & 15;
    const int gcb = gx0 + (cgs << 2);

    // Raw prefetch: rows of store-band b are base+16b+21+rr, loaded at band
    // start, h-blurred + stored at band end (R1-proven schedule).
    const float* p1 = base1 + (ptrdiff_t)(base + 21 + rr) * IMG + gcb - 8;
    const float* p2 = base2 + (ptrdiff_t)(base + 21 + rr) * IMG + gcb - 8;

    // ---- vertical blur + SSIM for one band (4 rows/thread)
    const int col  = tid & 63;
    const int rcol = col ^ (col >> 2);               // phys read col
    const int wv   = __builtin_amdgcn_readfirstlane(tid >> 6);

    auto vertical = [&](int sb_) {
        const int d0 = sb_ + (wv << 2);              // uniform, <= 36
        f2 ma[4] = {f2{0.f,0.f},f2{0.f,0.f},f2{0.f,0.f},f2{0.f,0.f}};
        f2 sa[4] = {f2{0.f,0.f},f2{0.f,0.f},f2{0.f,0.f},f2{0.f,0.f}};
        #pragma unroll
        for (int i = 0; i < 14; ++i) {
            int s = d0 + i;                          // <= 49 -> one cond sub
            s -= (s >= RING) ? RING : 0;
            const float4 q = sH[s][rcol];
            const f2 v = {q.x, q.y};                 // (bx, by)
            const f2 u = {q.z, q.w};                 // (bs, bp)
            #pragma unroll
            for (int o = 0; o < 4; ++o) {
                const int k = i - o;                 // tap index for row o
                if (0 <= k && k <= 10) {
                    ma[o] = pkfma(W2r[k], v, ma[o]);
                    sa[o] = pkfma(W2r[k], u, sa[o]);
                }
            }
        }
        #pragma unroll
        for (int o = 0; o < 4; ++o) {
            const f2 m   = ma[o];
            const f2 tt  = sa[o];
            const f2 msq = m * m;                    // (mu1^2, mu2^2)
            const float mu12  = m.x * m.y;
            const float musum = msq.x + msq.y;
            const float g12 = tt.y - mu12;           // sigma12
            const float gs  = tt.x - musum;          // sigma1^2 + sigma2^2
            const float num = fmaf(2.f, mu12, C1) * fmaf(2.f, g12, C2);
            const float den = (musum + C1) * (gs + C2);
            acc = fmaf(num, __builtin_amdgcn_rcpf(den), acc);
        }
    };

    // ---- prologue: h-blur rows base-5 .. base+20 into slots 0..25 (no mod)
    for (int task = tid; task < RING * 16; task += 256) {
        const int i   = task >> 4;                   // 0..25 == slot
        const int cg  = task & 15;
        const int gr  = base - HALO + i;             // max 384+20 < 512 always
        const int gcb2 = gx0 + (cg << 2);
        const float* r1 = base1 + (ptrdiff_t)gr * IMG + gcb2 - 8;
        const float* r2 = base2 + (ptrdiff_t)gr * IMG + gcb2 - 8;
        float4 qx[5], qy[5];
        if (!edge && gr >= 0) {
            #pragma unroll
            for (int t = 0; t < 5; ++t) {
                qx[t] = ((const float4*)r1)[t];
                qy[t] = ((const float4*)r2)[t];
            }
        } else {
            loadRowP(r1, r2, gr >= 0, gcb2, qx, qy);
        }
        horizStore(qx, qy, i, cg);
    }

    // ---- main loop (R1 schedule: load at band start, store at band end)
    int sb = 0;                                      // (16*b) mod RING, scalar
    for (int b = 0; b < NB; ++b) {
        float4 px[5], py[5];
        const bool pf = (b + 1 < NB);
        if (pf) {
            // rows OOB only possible when quarter==3 && b==NB-2 (501..516)
            const bool rowsafe = (quarter < 3) | (b < NB - 2);
            if (rowsafe & (!edge)) {
                #pragma unroll
                for (int t = 0; t < 5; ++t) {
                    px[t] = ((const float4*)p1)[t];
                    py[t] = ((const float4*)p2)[t];
                }
            } else {
                const int gr = base + (b << 4) + 21 + rr;
                loadRowP(p1, p2, (unsigned)gr < (unsigned)IMG, gcb, px, py);
            }
        }

        LGKM_BARRIER();                              // ring rows for band b ready
        vertical(sb);
        LGKM_BARRIER();                              // vert reads done (WAR on ring)

        if (pf) {
            int t = sb + rr;                         // (sb+26+rr) mod 26, <= 40
            t -= (t >= RING) ? RING : 0;
            horizStore(px, py, t, cgs);
            p1 += BAND * IMG;
            p2 += BAND * IMG;
        }
        sb += BAND; sb -= (sb >= RING) ? RING : 0;
    }

    // ---- block reduction -> one partial per block
    #pragma unroll
    for (int off = 32; off > 0; off >>= 1)
        acc += __shfl_down(acc, off, 64);
    if ((tid & 63) == 0) sRed[tid >> 6] = acc;
    LGKM_BARRIER();
    if (tid == 0) part[bx] = sRed[0] + sRed[1] + sRed[2] + sRed[3];
}

__global__ void ssim_finalize(const float* __restrict__ part, float* __restrict__ out)
{
    __shared__ double sD[4];
    double s = 0.0;
    const int t = threadIdx.x;
    for (int i = t; i < 2048; i += 256) s += (double)part[i];
    #pragma unroll
    for (int off = 32; off > 0; off >>= 1)
        s += __shfl_down(s, off, 64);
    if ((t & 63) == 0) sD[t >> 6] = s;
    __syncthreads();
    if (t == 0) out[0] = (float)((sD[0] + sD[1] + sD[2] + sD[3]) * (1.0 / 16777216.0));
}

extern "C" void kernel_launch(void* const* d_in, const int* in_sizes, int n_in,
                              void* d_out, int out_size, void* d_ws, size_t ws_size,
                              hipStream_t stream)
{
    const float* img1 = (const float*)d_in[0];
    const float* img2 = (const float*)d_in[1];
    float* out  = (float*)d_out;
    float* part = (float*)d_ws;      // 2048 floats of scratch

    ssim_main<<<2048, 256, 0, stream>>>(img1, img2, part);
    ssim_finalize<<<1, 256, 0, stream>>>(part, out);
}